// Round 1
// baseline (1239.335 us; speedup 1.0000x reference)
//
#include <hip/hip_runtime.h>
#include <hip/hip_bf16.h>

#define N_AG   4096
#define T_IN   8
#define PRELEN 12
#define EDIM   64
#define HDIM   128
#define KTOT   320    // E + H (x part, 192) + H (h part, 128)
#define GDIM   512    // 4*H

// ---------------- workspace layout (floats) ----------------
// h      : N*H           = 524288     @ 0
// c      : N*H           = 524288     @ 524288
// sh     : N*H           = 524288     @ 1048576
// last   : N*2           = 8192       @ 1572864
// Wt     : 320*512       = 163840     @ 1581056
// bsum   : 512           = 512        @ 1744896
// posAll : 7*N*2         = 57344      @ 1745408
// total ~ 1802752 floats = ~7.2 MB

// ---------------- init: zero h/c, build Wt/bsum/last/posAll/out[0:16] ----------------
__global__ __launch_bounds__(256) void init_kernel(
    const float* __restrict__ tracks,
    const float* __restrict__ Wih, const float* __restrict__ Whh,
    const float* __restrict__ bih, const float* __restrict__ bhh,
    float* __restrict__ h, float* __restrict__ c, float* __restrict__ last,
    float* __restrict__ Wt, float* __restrict__ bsum, float* __restrict__ posAll,
    float* __restrict__ out)
{
    int idx = blockIdx.x * 256 + threadIdx.x;   // grid covers 524288
    h[idx] = 0.f;
    c[idx] = 0.f;
    if (idx < KTOT * GDIM) {                     // Wt[k][g] = W[g][k]
        int k = idx >> 9, g = idx & 511;
        Wt[idx] = (k < 192) ? Wih[g * 192 + k] : Whh[g * 128 + (k - 192)];
    }
    if (idx < N_AG) {                            // last = tracks[:, 7]
        last[idx * 2 + 0] = tracks[idx * 16 + 14];
        last[idx * 2 + 1] = tracks[idx * 16 + 15];
    }
    if (idx < GDIM) bsum[idx] = bih[idx] + bhh[idx];
    if (idx < 16)  out[idx] = tracks[idx];       // out[0:8] = tracks[0] (agent 0, 8x2)
    if (idx < 7 * N_AG) {                        // posAll[t][a] = tracks[a, t]
        int t = idx / N_AG, a = idx & (N_AG - 1);
        posAll[idx * 2 + 0] = tracks[a * 16 + t * 2 + 0];
        posAll[idx * 2 + 1] = tracks[a * 16 + t * 2 + 1];
    }
}

// ---------------- social pool: sh[i] = sum_{j: |p_i-p_j|^2 < 25} h[j] ----------------
__global__ __launch_bounds__(256) void social_pool(
    const float* __restrict__ pos,      // compact N x 2
    const float* __restrict__ hbuf,     // N x 128
    float* __restrict__ sh)             // N x 128
{
    int i    = blockIdx.x;
    int lane = threadIdx.x & 63;
    int wv   = threadIdx.x >> 6;        // 0..3
    const float2* posv = (const float2*)pos;
    float2 pi = posv[i];
    float acc0 = 0.f, acc1 = 0.f;
    for (int base = wv * 64; base < N_AG; base += 256) {
        float2 pj = posv[base + lane];
        float dx = pj.x - pi.x, dy = pj.y - pi.y;
        unsigned long long m = __ballot(dx * dx + dy * dy < 25.0f);
        while (m) {                      // wave-uniform sparse walk
            int b = __ffsll(m) - 1;
            m &= m - 1;
            const float* hr = hbuf + (unsigned)(base + b) * HDIM;
            acc0 += hr[lane];
            acc1 += hr[lane + 64];
        }
    }
    __shared__ float red[4][HDIM];
    red[wv][lane]      = acc0;
    red[wv][lane + 64] = acc1;
    __syncthreads();
    int t = threadIdx.x;
    if (t < HDIM)
        sh[(unsigned)i * HDIM + t] = red[0][t] + red[1][t] + red[2][t] + red[3][t];
}

// ---------------- fused gates GEMM + LSTM cell update ----------------
// block: 16 agents x all 512 gate columns; 256 threads, 2 cols each
#define TI 16
__global__ __launch_bounds__(256) void lstm_step(
    const float* __restrict__ pos,      // compact N x 2
    const float* __restrict__ sh,       // N x 128 (ignored if firstStep)
    const float* __restrict__ We, const float* __restrict__ be,
    const float* __restrict__ Wt,       // 320 x 512 (k-major)
    const float* __restrict__ bsum,     // 512
    float* __restrict__ h, float* __restrict__ c,
    int firstStep)
{
    __shared__ __align__(16) float xs[TI][KTOT];   // 20 KB
    __shared__ __align__(16) float gs[TI][GDIM];   // 32 KB
    int a0  = blockIdx.x * TI;
    int tid = threadIdx.x;

    // stage x = [emb(pos) (64) | sh (128) | h (128)]
    for (int idx = tid; idx < TI * KTOT; idx += 256) {
        int a = idx / KTOT, k = idx - a * KTOT;
        int ga = a0 + a;
        float v;
        if (k < EDIM) {
            float px = pos[ga * 2], py = pos[ga * 2 + 1];
            v = fmaf(px, We[k * 2], fmaf(py, We[k * 2 + 1], be[k]));
        } else if (k < EDIM + HDIM) {
            v = firstStep ? 0.f : sh[(unsigned)ga * HDIM + (k - EDIM)];
        } else {
            v = h[(unsigned)ga * HDIM + (k - EDIM - HDIM)];  // zeroed at init for step 0
        }
        xs[a][k] = v;
    }
    __syncthreads();

    int g0 = tid, g1 = tid + 256;
    float acc0[TI], acc1[TI];
    float b0 = bsum[g0], b1 = bsum[g1];
#pragma unroll
    for (int a = 0; a < TI; a++) { acc0[a] = b0; acc1[a] = b1; }

    for (int k4 = 0; k4 < KTOT; k4 += 4) {
        float w00 = Wt[(k4 + 0) * GDIM + g0], w01 = Wt[(k4 + 1) * GDIM + g0];
        float w02 = Wt[(k4 + 2) * GDIM + g0], w03 = Wt[(k4 + 3) * GDIM + g0];
        float w10 = Wt[(k4 + 0) * GDIM + g1], w11 = Wt[(k4 + 1) * GDIM + g1];
        float w12 = Wt[(k4 + 2) * GDIM + g1], w13 = Wt[(k4 + 3) * GDIM + g1];
#pragma unroll
        for (int a = 0; a < TI; a++) {
            float4 xv = *(const float4*)&xs[a][k4];
            acc0[a] = fmaf(xv.x, w00, acc0[a]);
            acc0[a] = fmaf(xv.y, w01, acc0[a]);
            acc0[a] = fmaf(xv.z, w02, acc0[a]);
            acc0[a] = fmaf(xv.w, w03, acc0[a]);
            acc1[a] = fmaf(xv.x, w10, acc1[a]);
            acc1[a] = fmaf(xv.y, w11, acc1[a]);
            acc1[a] = fmaf(xv.z, w12, acc1[a]);
            acc1[a] = fmaf(xv.w, w13, acc1[a]);
        }
    }

#pragma unroll
    for (int a = 0; a < TI; a++) { gs[a][g0] = acc0[a]; gs[a][g1] = acc1[a]; }
    __syncthreads();

    // elementwise LSTM update: i,f,g,o at cols d, 128+d, 256+d, 384+d
    for (int idx = tid; idx < TI * HDIM; idx += 256) {
        int a = idx >> 7, d = idx & 127;
        int ga = a0 + a;
        float vi = gs[a][d], vf = gs[a][128 + d], vg = gs[a][256 + d], vo = gs[a][384 + d];
        float ig = 1.f / (1.f + expf(-vi));
        float fg = 1.f / (1.f + expf(-vf));
        float gg = tanhf(vg);
        float og = 1.f / (1.f + expf(-vo));
        float cn = fmaf(fg, c[(unsigned)ga * HDIM + d], ig * gg);
        float hn = og * tanhf(cn);
        c[(unsigned)ga * HDIM + d] = cn;
        h[(unsigned)ga * HDIM + d] = hn;
    }
}

// ---------------- decoder tail: delta = h@Wd^T + bd; last += delta; record agent 0 ----------------
__global__ __launch_bounds__(256) void decode_step(
    const float* __restrict__ h, const float* __restrict__ Wd,
    const float* __restrict__ bd, float* __restrict__ last,
    float* __restrict__ out, int step)
{
    int a    = blockIdx.x * 4 + (threadIdx.x >> 6);
    int lane = threadIdx.x & 63;
    const float* hr = h + (unsigned)a * HDIM;
    float h0 = hr[lane], h1 = hr[lane + 64];
    float dx = fmaf(h0, Wd[lane],       h1 * Wd[lane + 64]);
    float dy = fmaf(h0, Wd[128 + lane], h1 * Wd[192 + lane]);
#pragma unroll
    for (int off = 32; off; off >>= 1) {
        dx += __shfl_down(dx, off);
        dy += __shfl_down(dy, off);
    }
    if (lane == 0) {
        float lx = last[a * 2 + 0] + dx + bd[0];
        float ly = last[a * 2 + 1] + dy + bd[1];
        last[a * 2 + 0] = lx;
        last[a * 2 + 1] = ly;
        if (a == 0) {
            out[(8 + step) * 2 + 0] = lx;
            out[(8 + step) * 2 + 1] = ly;
        }
    }
}

extern "C" void kernel_launch(void* const* d_in, const int* in_sizes, int n_in,
                              void* d_out, int out_size, void* d_ws, size_t ws_size,
                              hipStream_t stream)
{
    const float* tracks = (const float*)d_in[0];
    const float* We     = (const float*)d_in[1];
    const float* be     = (const float*)d_in[2];
    const float* Wih    = (const float*)d_in[3];
    const float* Whh    = (const float*)d_in[4];
    const float* bih    = (const float*)d_in[5];
    const float* bhh    = (const float*)d_in[6];
    const float* Wd     = (const float*)d_in[7];
    const float* bd     = (const float*)d_in[8];
    float* out = (float*)d_out;
    float* ws  = (float*)d_ws;

    float* h      = ws;
    float* c      = ws + 524288;
    float* sh     = ws + 1048576;
    float* last   = ws + 1572864;
    float* Wt     = ws + 1581056;
    float* bsum   = ws + 1744896;
    float* posAll = ws + 1745408;

    init_kernel<<<2048, 256, 0, stream>>>(tracks, Wih, Whh, bih, bhh,
                                          h, c, last, Wt, bsum, posAll, out);

    // step 0: x0 = [emb(tracks[:,0]) | zeros], h=c=0
    lstm_step<<<N_AG / TI, 256, 0, stream>>>(posAll, nullptr, We, be, Wt, bsum, h, c, 1);

    // encoder: t = 0..6
    for (int t = 0; t < T_IN - 1; t++) {
        const float* pos = posAll + (size_t)t * N_AG * 2;
        social_pool<<<N_AG, 256, 0, stream>>>(pos, h, sh);
        lstm_step<<<N_AG / TI, 256, 0, stream>>>(pos, sh, We, be, Wt, bsum, h, c, 0);
    }

    // decoder: 12 steps
    for (int s = 0; s < PRELEN; s++) {
        social_pool<<<N_AG, 256, 0, stream>>>(last, h, sh);
        lstm_step<<<N_AG / TI, 256, 0, stream>>>(last, sh, We, be, Wt, bsum, h, c, 0);
        decode_step<<<N_AG / 4, 256, 0, stream>>>(h, Wd, bd, last, out, s);
    }
}

// Round 3
// 1151.577 us; speedup vs baseline: 1.0762x; 1.0762x over previous
//
#include <hip/hip_runtime.h>
#include <hip/hip_bf16.h>

#define N_AG   4096
#define T_IN   8
#define PRELEN 12
#define EDIM   64
#define HDIM   128
#define KTOT   320    // E + H (sh) + H (h)
#define GDIM   512    // 4*H
#define KI     10     // KTOT / 32
#define LOSCALE 2048.0f

typedef _Float16 f16x8 __attribute__((ext_vector_type(8)));
typedef float    f32x4 __attribute__((ext_vector_type(4)));

// ---------------- workspace layout (float units) ----------------
// h      @ 0        (524288)
// c      @ 524288   (524288)
// sh     @ 1048576  (524288)
// last   @ 1572864  (8192)
// bsum   @ 1581056  (512)
// posAll @ 1581568  (57344)
// WfragH @ 1638912  (81920 floats = 163840 f16)
// WfragL @ 1720832  (81920 floats = 163840 f16)   total ~7.2 MB

// ---------------- init ----------------
__global__ __launch_bounds__(256) void init_kernel(
    const float* __restrict__ tracks,
    const float* __restrict__ Wih, const float* __restrict__ Whh,
    const float* __restrict__ bih, const float* __restrict__ bhh,
    float* __restrict__ h, float* __restrict__ c, float* __restrict__ last,
    _Float16* __restrict__ WfH, _Float16* __restrict__ WfL,
    float* __restrict__ bsum, float* __restrict__ posAll, float* __restrict__ out)
{
    int idx = blockIdx.x * 256 + threadIdx.x;   // grid covers 524288
    h[idx] = 0.f;
    c[idx] = 0.f;
    if (idx < KTOT * GDIM) {                    // pack W into MFMA fragment order, split f16
        int g = idx / KTOT, k = idx - g * KTOT; // g = gate col, k = contraction idx
        float val = (k < 192) ? Wih[g * 192 + k] : Whh[g * 128 + (k - 192)];
        int nt = g >> 4, ki = k >> 5;
        int ln = (g & 15) | (((k >> 3) & 3) << 4);
        int e  = k & 7;
        size_t off = (size_t)((nt * KI + ki) * 64 + ln) * 8 + e;
        _Float16 hi = (_Float16)val;
        WfH[off] = hi;
        WfL[off] = (_Float16)((val - (float)hi) * LOSCALE);
    }
    if (idx < N_AG) {                           // last = tracks[:, 7]
        last[idx * 2 + 0] = tracks[idx * 16 + 14];
        last[idx * 2 + 1] = tracks[idx * 16 + 15];
    }
    if (idx < GDIM) bsum[idx] = bih[idx] + bhh[idx];
    if (idx < 16)  out[idx] = tracks[idx];      // out[0:8] = tracks[0]
    if (idx < 7 * N_AG) {                       // posAll[t][a] = tracks[a, t]
        int t = idx / N_AG, a = idx & (N_AG - 1);
        posAll[idx * 2 + 0] = tracks[a * 16 + t * 2 + 0];
        posAll[idx * 2 + 1] = tracks[a * 16 + t * 2 + 1];
    }
}

// ---------------- social pool: one wave per agent ----------------
__global__ __launch_bounds__(256) void social_pool(
    const float* __restrict__ pos,      // compact N x 2
    const float* __restrict__ hbuf,     // N x 128
    float* __restrict__ sh)             // N x 128
{
    int lane = threadIdx.x & 63;
    int wv   = threadIdx.x >> 6;
    int i    = blockIdx.x * 4 + wv;
    const float2* posv = (const float2*)pos;
    float2 pi = posv[i];
    float acc0 = 0.f, acc1 = 0.f;
    for (int base = 0; base < N_AG; base += 64) {
        float2 pj = posv[base + lane];
        float dx = pj.x - pi.x, dy = pj.y - pi.y;
        unsigned long long m = __ballot(dx * dx + dy * dy < 25.0f);
        while (m) {                      // wave-uniform sparse walk
            int b = __ffsll(m) - 1;
            m &= m - 1;
            const float* hr = hbuf + (unsigned)(base + b) * HDIM;
            acc0 += hr[lane];
            acc1 += hr[lane + 64];
        }
    }
    sh[(unsigned)i * HDIM + lane]      = acc0;
    sh[(unsigned)i * HDIM + 64 + lane] = acc1;
}

// ---------------- fused MFMA gates GEMM + LSTM update ----------------
// block: 64 agents x 1/4 of dcols (32 d-values, all 4 gates). 256 blocks, 512 thr.
// wave w: m-tile (w&3) of 16 agents, dcol group n0 = 2*cg + (w>>2);
// its 4 ntiles {n0, n0+8, n0+16, n0+24} = i,f,g,o for its 16 dcols ->
// LSTM pointwise update entirely in registers.
__global__ __launch_bounds__(512) void lstm_step(
    const float* __restrict__ pos,      // compact N x 2
    const float* __restrict__ sh,       // N x 128
    const float* __restrict__ We, const float* __restrict__ be,
    const _Float16* __restrict__ WfH,   // [32 nt][10 ki][64 ln][8] f16 hi
    const _Float16* __restrict__ WfL,   // same, lo*2048
    const float* __restrict__ bsum,
    float* __restrict__ h, float* __restrict__ c,
    int firstStep)
{
    __shared__ __align__(16) _Float16 AH[4][KI][64][8];   // 40 KB
    __shared__ __align__(16) _Float16 AL[4][KI][64][8];   // 40 KB
    int cg  = blockIdx.x & 3;
    int a0  = (blockIdx.x >> 2) * 64;
    int tid = threadIdx.x;

    // ---- stage x = [emb(pos) | sh | h] for 64 agents as split-f16 fragments ----
    for (int u = tid; u < 64 * (KTOT / 8); u += 512) {  // 2560 units
        int a = u / 40, kg = u - a * 40;
        int ga = a0 + a;
        int k0 = kg * 8;
        float v[8];
        if (k0 < EDIM) {
            float px = pos[ga * 2], py = pos[ga * 2 + 1];
#pragma unroll
            for (int j = 0; j < 8; j++) {
                int k = k0 + j;
                v[j] = fmaf(px, We[k * 2], fmaf(py, We[k * 2 + 1], be[k]));
            }
        } else if (k0 < EDIM + HDIM) {
#pragma unroll
            for (int j = 0; j < 8; j++)
                v[j] = firstStep ? 0.f : sh[(unsigned)ga * HDIM + (k0 - EDIM + j)];
        } else {
#pragma unroll
            for (int j = 0; j < 8; j++)
                v[j] = h[(unsigned)ga * HDIM + (k0 - EDIM - HDIM + j)];
        }
        f16x8 hi8, lo8;
#pragma unroll
        for (int j = 0; j < 8; j++) {
            _Float16 hv = (_Float16)v[j];
            hi8[j] = hv;
            lo8[j] = (_Float16)((v[j] - (float)hv) * LOSCALE);
        }
        int m = a >> 4, ki = kg >> 2, ln = (a & 15) | ((kg & 3) << 4);
        *(f16x8*)&AH[m][ki][ln][0] = hi8;
        *(f16x8*)&AL[m][ki][ln][0] = lo8;
    }
    __syncthreads();

    int wave = tid >> 6, lane = tid & 63;
    int m  = wave & 3;
    int ng = wave >> 2;
    int n0 = 2 * cg + ng;
    int dcol = 32 * cg + 16 * ng + (lane & 15);

    f32x4 acc[4], accL[4];
#pragma unroll
    for (int g = 0; g < 4; g++) {
        float bb = bsum[dcol + g * 128];
        f32x4 z; z[0] = bb; z[1] = bb; z[2] = bb; z[3] = bb;
        acc[g] = z;
        f32x4 zz; zz[0] = 0.f; zz[1] = 0.f; zz[2] = 0.f; zz[3] = 0.f;
        accL[g] = zz;
    }

#pragma unroll
    for (int ki = 0; ki < KI; ki++) {
        f16x8 ah = *(const f16x8*)&AH[m][ki][lane][0];
        f16x8 al = *(const f16x8*)&AL[m][ki][lane][0];
#pragma unroll
        for (int g = 0; g < 4; g++) {
            int nt = n0 + 8 * g;
            size_t off = (size_t)((nt * KI + ki) * 64 + lane) * 8;
            f16x8 bh = *(const f16x8*)&WfH[off];
            f16x8 bl = *(const f16x8*)&WfL[off];
            acc[g]  = __builtin_amdgcn_mfma_f32_16x16x32_f16(ah, bh, acc[g],  0, 0, 0);
            accL[g] = __builtin_amdgcn_mfma_f32_16x16x32_f16(al, bh, accL[g], 0, 0, 0);
            accL[g] = __builtin_amdgcn_mfma_f32_16x16x32_f16(ah, bl, accL[g], 0, 0, 0);
        }
    }

    // ---- LSTM pointwise update, fully in registers ----
    const float inv = 1.0f / LOSCALE;
#pragma unroll
    for (int r = 0; r < 4; r++) {
        int alc = (lane >> 4) * 4 + r;      // row within m-tile (C/D mapping)
        int ga  = a0 + 16 * m + alc;
        float vi = fmaf(accL[0][r], inv, acc[0][r]);
        float vf = fmaf(accL[1][r], inv, acc[1][r]);
        float vg = fmaf(accL[2][r], inv, acc[2][r]);
        float vo = fmaf(accL[3][r], inv, acc[3][r]);
        float ig = 1.f / (1.f + expf(-vi));
        float fg = 1.f / (1.f + expf(-vf));
        float gg = tanhf(vg);
        float og = 1.f / (1.f + expf(-vo));
        float cold = c[(unsigned)ga * HDIM + dcol];
        float cn = fmaf(fg, cold, ig * gg);
        float hn = og * tanhf(cn);
        c[(unsigned)ga * HDIM + dcol] = cn;
        h[(unsigned)ga * HDIM + dcol] = hn;
    }
}

// ---------------- decoder tail: delta = h@Wd^T + bd; last += delta ----------------
__global__ __launch_bounds__(256) void decode_step(
    const float* __restrict__ h, const float* __restrict__ Wd,
    const float* __restrict__ bd, float* __restrict__ last,
    float* __restrict__ out, int step)
{
    int a    = blockIdx.x * 4 + (threadIdx.x >> 6);
    int lane = threadIdx.x & 63;
    const float* hr = h + (unsigned)a * HDIM;
    float h0 = hr[lane], h1 = hr[lane + 64];
    float dx = fmaf(h0, Wd[lane],       h1 * Wd[lane + 64]);
    float dy = fmaf(h0, Wd[128 + lane], h1 * Wd[192 + lane]);
#pragma unroll
    for (int off = 32; off; off >>= 1) {
        dx += __shfl_down(dx, off);
        dy += __shfl_down(dy, off);
    }
    if (lane == 0) {
        float lx = last[a * 2 + 0] + dx + bd[0];
        float ly = last[a * 2 + 1] + dy + bd[1];
        last[a * 2 + 0] = lx;
        last[a * 2 + 1] = ly;
        if (a == 0) {
            out[(8 + step) * 2 + 0] = lx;
            out[(8 + step) * 2 + 1] = ly;
        }
    }
}

extern "C" void kernel_launch(void* const* d_in, const int* in_sizes, int n_in,
                              void* d_out, int out_size, void* d_ws, size_t ws_size,
                              hipStream_t stream)
{
    const float* tracks = (const float*)d_in[0];
    const float* We     = (const float*)d_in[1];
    const float* be     = (const float*)d_in[2];
    const float* Wih    = (const float*)d_in[3];
    const float* Whh    = (const float*)d_in[4];
    const float* bih    = (const float*)d_in[5];
    const float* bhh    = (const float*)d_in[6];
    const float* Wd     = (const float*)d_in[7];
    const float* bd     = (const float*)d_in[8];
    float* out = (float*)d_out;
    float* ws  = (float*)d_ws;

    float*     h      = ws;
    float*     c      = ws + 524288;
    float*     sh     = ws + 1048576;
    float*     last   = ws + 1572864;
    float*     bsum   = ws + 1581056;
    float*     posAll = ws + 1581568;
    _Float16*  WfH    = (_Float16*)(ws + 1638912);
    _Float16*  WfL    = (_Float16*)(ws + 1720832);

    init_kernel<<<2048, 256, 0, stream>>>(tracks, Wih, Whh, bih, bhh,
                                          h, c, last, WfH, WfL, bsum, posAll, out);

    // step 0: x0 = [emb(tracks[:,0]) | zeros], h=c=0
    lstm_step<<<256, 512, 0, stream>>>(posAll, sh, We, be, WfH, WfL, bsum, h, c, 1);

    // encoder: t = 0..6
    for (int t = 0; t < T_IN - 1; t++) {
        const float* pos = posAll + (size_t)t * N_AG * 2;
        social_pool<<<N_AG / 4, 256, 0, stream>>>(pos, h, sh);
        lstm_step<<<256, 512, 0, stream>>>(pos, sh, We, be, WfH, WfL, bsum, h, c, 0);
    }

    // decoder: 12 steps
    for (int s = 0; s < PRELEN; s++) {
        social_pool<<<N_AG / 4, 256, 0, stream>>>(last, h, sh);
        lstm_step<<<256, 512, 0, stream>>>(last, sh, We, be, WfH, WfL, bsum, h, c, 0);
        decode_step<<<N_AG / 4, 256, 0, stream>>>(h, Wd, bd, last, out, s);
    }
}

// Round 4
// 857.262 us; speedup vs baseline: 1.4457x; 1.3433x over previous
//
#include <hip/hip_runtime.h>
#include <hip/hip_bf16.h>

#define N_AG   4096
#define T_IN   8
#define PRELEN 12
#define EDIM   64
#define HDIM   128
#define KTOT   320    // E + H (sh) + H (h)
#define GDIM   512    // 4*H
#define KI     10     // KTOT / 32
#define LOSCALE 2048.0f

typedef _Float16 f16x8 __attribute__((ext_vector_type(8)));
typedef float    f32x4 __attribute__((ext_vector_type(4)));

// ---------------- workspace layout (float units) ----------------
// h      @ 0        (524288)
// c      @ 524288   (524288)
// sh     @ 1048576  (524288)
// last   @ 1572864  (8192)
// bsum   @ 1581056  (512)
// posAll @ 1581568  (57344)
// WfragH @ 1638912  (81920 floats = 163840 f16)
// WfragL @ 1720832  (81920 floats = 163840 f16)   total ~7.2 MB

// ---------------- init ----------------
__global__ __launch_bounds__(256) void init_kernel(
    const float* __restrict__ tracks,
    const float* __restrict__ Wih, const float* __restrict__ Whh,
    const float* __restrict__ bih, const float* __restrict__ bhh,
    float* __restrict__ h, float* __restrict__ c, float* __restrict__ last,
    _Float16* __restrict__ WfH, _Float16* __restrict__ WfL,
    float* __restrict__ bsum, float* __restrict__ posAll, float* __restrict__ out)
{
    int idx = blockIdx.x * 256 + threadIdx.x;   // grid covers 524288
    h[idx] = 0.f;
    c[idx] = 0.f;
    if (idx < KTOT * GDIM) {                    // pack W into MFMA fragment order, split f16
        int g = idx / KTOT, k = idx - g * KTOT; // g = gate col, k = contraction idx
        float val = (k < 192) ? Wih[g * 192 + k] : Whh[g * 128 + (k - 192)];
        int nt = g >> 4, ki = k >> 5;
        int ln = (g & 15) | (((k >> 3) & 3) << 4);
        int e  = k & 7;
        size_t off = (size_t)((nt * KI + ki) * 64 + ln) * 8 + e;
        _Float16 hi = (_Float16)val;
        WfH[off] = hi;
        WfL[off] = (_Float16)((val - (float)hi) * LOSCALE);
    }
    if (idx < N_AG) {                           // last = tracks[:, 7]
        last[idx * 2 + 0] = tracks[idx * 16 + 14];
        last[idx * 2 + 1] = tracks[idx * 16 + 15];
    }
    if (idx < GDIM) bsum[idx] = bih[idx] + bhh[idx];
    if (idx < 16)  out[idx] = tracks[idx];      // out[0:8] = tracks[0]
    if (idx < 7 * N_AG) {                       // posAll[t][a] = tracks[a, t]
        int t = idx / N_AG, a = idx & (N_AG - 1);
        posAll[idx * 2 + 0] = tracks[a * 16 + t * 2 + 0];
        posAll[idx * 2 + 1] = tracks[a * 16 + t * 2 + 1];
    }
}

// ---------------- social pool: 8 waves per agent, interleaved j-chunks ----------------
__global__ __launch_bounds__(512) void social_pool(
    const float* __restrict__ pos,      // compact N x 2
    const float* __restrict__ hbuf,     // N x 128
    float* __restrict__ sh)             // N x 128
{
    int i    = blockIdx.x;
    int lane = threadIdx.x & 63;
    int wv   = threadIdx.x >> 6;        // 0..7
    const float2* posv = (const float2*)pos;
    float2 pi = posv[i];
    float acc0 = 0.f, acc1 = 0.f;
#pragma unroll
    for (int cc = 0; cc < 8; cc++) {    // 8 chunks per wave, compile-time trip
        int base = wv * 64 + cc * 512;
        float2 pj = posv[base + lane];
        float dx = pj.x - pi.x, dy = pj.y - pi.y;
        unsigned long long m = __ballot(dx * dx + dy * dy < 25.0f);
        while (m) {                      // wave-uniform sparse walk
            int b = __ffsll(m) - 1;
            m &= m - 1;
            const float* hr = hbuf + (unsigned)(base + b) * HDIM;
            acc0 += hr[lane];
            acc1 += hr[lane + 64];
        }
    }
    __shared__ float red[8][HDIM];
    red[wv][lane]      = acc0;
    red[wv][lane + 64] = acc1;
    __syncthreads();
    int t = threadIdx.x;
    if (t < HDIM) {
        float s = red[0][t] + red[1][t] + red[2][t] + red[3][t]
                + red[4][t] + red[5][t] + red[6][t] + red[7][t];
        sh[(unsigned)i * HDIM + t] = s;
    }
}

// ---------------- fused MFMA gates GEMM + LSTM update ----------------
// block: 64 agents x 1/4 of dcols (32 d-values, all 4 gates). 256 blocks, 512 thr.
// wave w: m-tile (w&3) of 16 agents, dcol group n0 = 2*cg + (w>>2);
// its 4 ntiles {n0, n0+8, n0+16, n0+24} = i,f,g,o for its 16 dcols ->
// LSTM pointwise update entirely in registers.
__global__ __launch_bounds__(512) void lstm_step(
    const float* __restrict__ pos,      // compact N x 2
    const float* __restrict__ sh,       // N x 128
    const float* __restrict__ We, const float* __restrict__ be,
    const _Float16* __restrict__ WfH,   // [32 nt][10 ki][64 ln][8] f16 hi
    const _Float16* __restrict__ WfL,   // same, lo*2048
    const float* __restrict__ bsum,
    float* __restrict__ h, float* __restrict__ c,
    int firstStep)
{
    __shared__ __align__(16) _Float16 AH[4][KI][64][8];   // 40 KB
    __shared__ __align__(16) _Float16 AL[4][KI][64][8];   // 40 KB
    int cg  = blockIdx.x & 3;
    int a0  = (blockIdx.x >> 2) * 64;
    int tid = threadIdx.x;

    // ---- stage x = [emb(pos) | sh | h] for 64 agents as split-f16 fragments ----
    for (int u = tid; u < 64 * (KTOT / 8); u += 512) {  // 2560 units
        int a = u / 40, kg = u - a * 40;
        int ga = a0 + a;
        int k0 = kg * 8;
        float v[8];
        if (k0 < EDIM) {
            float px = pos[ga * 2], py = pos[ga * 2 + 1];
#pragma unroll
            for (int j = 0; j < 8; j++) {
                int k = k0 + j;
                v[j] = fmaf(px, We[k * 2], fmaf(py, We[k * 2 + 1], be[k]));
            }
        } else if (k0 < EDIM + HDIM) {
#pragma unroll
            for (int j = 0; j < 8; j++)
                v[j] = firstStep ? 0.f : sh[(unsigned)ga * HDIM + (k0 - EDIM + j)];
        } else {
#pragma unroll
            for (int j = 0; j < 8; j++)
                v[j] = h[(unsigned)ga * HDIM + (k0 - EDIM - HDIM + j)];
        }
        f16x8 hi8, lo8;
#pragma unroll
        for (int j = 0; j < 8; j++) {
            _Float16 hv = (_Float16)v[j];
            hi8[j] = hv;
            lo8[j] = (_Float16)((v[j] - (float)hv) * LOSCALE);
        }
        int m = a >> 4, ki = kg >> 2, ln = (a & 15) | ((kg & 3) << 4);
        *(f16x8*)&AH[m][ki][ln][0] = hi8;
        *(f16x8*)&AL[m][ki][ln][0] = lo8;
    }
    __syncthreads();

    int wave = tid >> 6, lane = tid & 63;
    int m  = wave & 3;
    int ng = wave >> 2;
    int n0 = 2 * cg + ng;
    int dcol = 32 * cg + 16 * ng + (lane & 15);

    f32x4 acc[4], accL[4];
#pragma unroll
    for (int g = 0; g < 4; g++) {
        float bb = bsum[dcol + g * 128];
        f32x4 z; z[0] = bb; z[1] = bb; z[2] = bb; z[3] = bb;
        acc[g] = z;
        f32x4 zz; zz[0] = 0.f; zz[1] = 0.f; zz[2] = 0.f; zz[3] = 0.f;
        accL[g] = zz;
    }

#pragma unroll
    for (int ki = 0; ki < KI; ki++) {
        f16x8 ah = *(const f16x8*)&AH[m][ki][lane][0];
        f16x8 al = *(const f16x8*)&AL[m][ki][lane][0];
#pragma unroll
        for (int g = 0; g < 4; g++) {
            int nt = n0 + 8 * g;
            size_t off = (size_t)((nt * KI + ki) * 64 + lane) * 8;
            f16x8 bh = *(const f16x8*)&WfH[off];
            f16x8 bl = *(const f16x8*)&WfL[off];
            acc[g]  = __builtin_amdgcn_mfma_f32_16x16x32_f16(ah, bh, acc[g],  0, 0, 0);
            accL[g] = __builtin_amdgcn_mfma_f32_16x16x32_f16(al, bh, accL[g], 0, 0, 0);
            accL[g] = __builtin_amdgcn_mfma_f32_16x16x32_f16(ah, bl, accL[g], 0, 0, 0);
        }
    }

    // ---- LSTM pointwise update, fully in registers ----
    const float inv = 1.0f / LOSCALE;
#pragma unroll
    for (int r = 0; r < 4; r++) {
        int alc = (lane >> 4) * 4 + r;      // row within m-tile (C/D mapping)
        int ga  = a0 + 16 * m + alc;
        float vi = fmaf(accL[0][r], inv, acc[0][r]);
        float vf = fmaf(accL[1][r], inv, acc[1][r]);
        float vg = fmaf(accL[2][r], inv, acc[2][r]);
        float vo = fmaf(accL[3][r], inv, acc[3][r]);
        float ig = 1.f / (1.f + expf(-vi));
        float fg = 1.f / (1.f + expf(-vf));
        float gg = tanhf(vg);
        float og = 1.f / (1.f + expf(-vo));
        float cold = c[(unsigned)ga * HDIM + dcol];
        float cn = fmaf(fg, cold, ig * gg);
        float hn = og * tanhf(cn);
        c[(unsigned)ga * HDIM + dcol] = cn;
        h[(unsigned)ga * HDIM + dcol] = hn;
    }
}

// ---------------- decoder tail: delta = h@Wd^T + bd; last += delta ----------------
__global__ __launch_bounds__(256) void decode_step(
    const float* __restrict__ h, const float* __restrict__ Wd,
    const float* __restrict__ bd, float* __restrict__ last,
    float* __restrict__ out, int step)
{
    int a    = blockIdx.x * 4 + (threadIdx.x >> 6);
    int lane = threadIdx.x & 63;
    const float* hr = h + (unsigned)a * HDIM;
    float h0 = hr[lane], h1 = hr[lane + 64];
    float dx = fmaf(h0, Wd[lane],       h1 * Wd[lane + 64]);
    float dy = fmaf(h0, Wd[128 + lane], h1 * Wd[192 + lane]);
#pragma unroll
    for (int off = 32; off; off >>= 1) {
        dx += __shfl_down(dx, off);
        dy += __shfl_down(dy, off);
    }
    if (lane == 0) {
        float lx = last[a * 2 + 0] + dx + bd[0];
        float ly = last[a * 2 + 1] + dy + bd[1];
        last[a * 2 + 0] = lx;
        last[a * 2 + 1] = ly;
        if (a == 0) {
            out[(8 + step) * 2 + 0] = lx;
            out[(8 + step) * 2 + 1] = ly;
        }
    }
}

extern "C" void kernel_launch(void* const* d_in, const int* in_sizes, int n_in,
                              void* d_out, int out_size, void* d_ws, size_t ws_size,
                              hipStream_t stream)
{
    const float* tracks = (const float*)d_in[0];
    const float* We     = (const float*)d_in[1];
    const float* be     = (const float*)d_in[2];
    const float* Wih    = (const float*)d_in[3];
    const float* Whh    = (const float*)d_in[4];
    const float* bih    = (const float*)d_in[5];
    const float* bhh    = (const float*)d_in[6];
    const float* Wd     = (const float*)d_in[7];
    const float* bd     = (const float*)d_in[8];
    float* out = (float*)d_out;
    float* ws  = (float*)d_ws;

    float*     h      = ws;
    float*     c      = ws + 524288;
    float*     sh     = ws + 1048576;
    float*     last   = ws + 1572864;
    float*     bsum   = ws + 1581056;
    float*     posAll = ws + 1581568;
    _Float16*  WfH    = (_Float16*)(ws + 1638912);
    _Float16*  WfL    = (_Float16*)(ws + 1720832);

    init_kernel<<<2048, 256, 0, stream>>>(tracks, Wih, Whh, bih, bhh,
                                          h, c, last, WfH, WfL, bsum, posAll, out);

    // step 0: x0 = [emb(tracks[:,0]) | zeros], h=c=0
    lstm_step<<<256, 512, 0, stream>>>(posAll, sh, We, be, WfH, WfL, bsum, h, c, 1);

    // encoder: t = 0..6
    for (int t = 0; t < T_IN - 1; t++) {
        const float* pos = posAll + (size_t)t * N_AG * 2;
        social_pool<<<N_AG, 512, 0, stream>>>(pos, h, sh);
        lstm_step<<<256, 512, 0, stream>>>(pos, sh, We, be, WfH, WfL, bsum, h, c, 0);
    }

    // decoder: 12 steps
    for (int s = 0; s < PRELEN; s++) {
        social_pool<<<N_AG, 512, 0, stream>>>(last, h, sh);
        lstm_step<<<256, 512, 0, stream>>>(last, sh, We, be, WfH, WfL, bsum, h, c, 0);
        decode_step<<<N_AG / 4, 256, 0, stream>>>(h, Wd, bd, last, out, s);
    }
}

// Round 5
// 787.107 us; speedup vs baseline: 1.5745x; 1.0891x over previous
//
#include <hip/hip_runtime.h>
#include <hip/hip_bf16.h>

#define N_AG   4096
#define T_IN   8
#define PRELEN 12
#define EDIM   64
#define HDIM   128
#define KTOT   320    // E + H (sh) + H (h)
#define GDIM   512    // 4*H
#define KI     10     // KTOT / 32
#define LOSCALE 2048.0f

typedef _Float16 f16x8 __attribute__((ext_vector_type(8)));
typedef float    f32x4 __attribute__((ext_vector_type(4)));

// ---------------- workspace layout (float units) ----------------
// h      @ 0        (524288)
// c      @ 524288   (524288)
// sh     @ 1048576  (524288)
// last   @ 1572864  (8192)
// bsum   @ 1581056  (512)
// posAll @ 1581568  (57344)
// WfragH @ 1638912  (81920 floats = 163840 f16)
// WfragL @ 1720832  (81920 floats = 163840 f16)   total ~7.2 MB

// ---------------- init ----------------
__global__ __launch_bounds__(256) void init_kernel(
    const float* __restrict__ tracks,
    const float* __restrict__ Wih, const float* __restrict__ Whh,
    const float* __restrict__ bih, const float* __restrict__ bhh,
    float* __restrict__ h, float* __restrict__ c, float* __restrict__ last,
    _Float16* __restrict__ WfH, _Float16* __restrict__ WfL,
    float* __restrict__ bsum, float* __restrict__ posAll, float* __restrict__ out)
{
    int idx = blockIdx.x * 256 + threadIdx.x;   // grid covers 524288
    h[idx] = 0.f;
    c[idx] = 0.f;
    if (idx < KTOT * GDIM) {                    // pack W into MFMA fragment order, split f16
        int g = idx / KTOT, k = idx - g * KTOT; // g = gate col, k = contraction idx
        float val = (k < 192) ? Wih[g * 192 + k] : Whh[g * 128 + (k - 192)];
        int nt = g >> 4, ki = k >> 5;
        int ln = (g & 15) | (((k >> 3) & 3) << 4);
        int e  = k & 7;
        size_t off = (size_t)((nt * KI + ki) * 64 + ln) * 8 + e;
        _Float16 hi = (_Float16)val;
        WfH[off] = hi;
        WfL[off] = (_Float16)((val - (float)hi) * LOSCALE);
    }
    if (idx < N_AG) {                           // last = tracks[:, 7]
        last[idx * 2 + 0] = tracks[idx * 16 + 14];
        last[idx * 2 + 1] = tracks[idx * 16 + 15];
    }
    if (idx < GDIM) bsum[idx] = bih[idx] + bhh[idx];
    if (idx < 16)  out[idx] = tracks[idx];      // out[0:8] = tracks[0]
    if (idx < 7 * N_AG) {                       // posAll[t][a] = tracks[a, t]
        int t = idx / N_AG, a = idx & (N_AG - 1);
        posAll[idx * 2 + 0] = tracks[a * 16 + t * 2 + 0];
        posAll[idx * 2 + 1] = tracks[a * 16 + t * 2 + 1];
    }
}

// ---------------- social pool: 8 waves/agent; ballot-rank collect + unrolled gather ----
__global__ __launch_bounds__(512) void social_pool(
    const float* __restrict__ pos,      // compact N x 2
    const float* __restrict__ hbuf,     // N x 128
    float* __restrict__ sh)             // N x 128
{
    __shared__ unsigned short idxbuf[8][512];   // 8 KB neighbor lists (worst case full)
    __shared__ float red[8][HDIM];              // 4 KB
    int i    = blockIdx.x;
    int lane = threadIdx.x & 63;
    int wv   = threadIdx.x >> 6;        // 0..7
    const float2* posv = (const float2*)pos;
    float2 pi = posv[i];

    // ---- phase 1: parallel neighbor-index collection (no serial walk) ----
    int cntw = 0;                        // wave-uniform running count
#pragma unroll
    for (int cc = 0; cc < 8; cc++) {
        int base = wv * 64 + cc * 512;
        float2 pj = posv[base + lane];
        float dx = pj.x - pi.x, dy = pj.y - pi.y;
        bool pred = (dx * dx + dy * dy < 25.0f);
        unsigned long long m = __ballot(pred);
        if (pred) {
            int rank = __popcll(m & ((1ull << lane) - 1ull));
            idxbuf[wv][cntw + rank] = (unsigned short)(base + lane);
        }
        cntw += __popcll(m);
    }

    // ---- phase 2: gather-sum, 4 independent accumulator chains ----
    float s0a = 0.f, s0b = 0.f, s1a = 0.f, s1b = 0.f;
    float s2a = 0.f, s2b = 0.f, s3a = 0.f, s3b = 0.f;
    int t = 0;
    for (; t + 4 <= cntw; t += 4) {
        int j0 = idxbuf[wv][t + 0], j1 = idxbuf[wv][t + 1];
        int j2 = idxbuf[wv][t + 2], j3 = idxbuf[wv][t + 3];
        const float* r0 = hbuf + (unsigned)j0 * HDIM;
        const float* r1 = hbuf + (unsigned)j1 * HDIM;
        const float* r2 = hbuf + (unsigned)j2 * HDIM;
        const float* r3 = hbuf + (unsigned)j3 * HDIM;
        s0a += r0[lane]; s0b += r0[lane + 64];
        s1a += r1[lane]; s1b += r1[lane + 64];
        s2a += r2[lane]; s2b += r2[lane + 64];
        s3a += r3[lane]; s3b += r3[lane + 64];
    }
    for (; t < cntw; t++) {
        int j = idxbuf[wv][t];
        const float* r = hbuf + (unsigned)j * HDIM;
        s0a += r[lane]; s0b += r[lane + 64];
    }
    float acc0 = (s0a + s1a) + (s2a + s3a);
    float acc1 = (s0b + s1b) + (s2b + s3b);

    red[wv][lane]      = acc0;
    red[wv][lane + 64] = acc1;
    __syncthreads();
    int tt = threadIdx.x;
    if (tt < HDIM) {
        float s = red[0][tt] + red[1][tt] + red[2][tt] + red[3][tt]
                + red[4][tt] + red[5][tt] + red[6][tt] + red[7][tt];
        sh[(unsigned)i * HDIM + tt] = s;
    }
}

// ---------------- fused MFMA gates GEMM + LSTM update ----------------
// block: 64 agents x 1/4 of dcols (32 d-values, all 4 gates). 256 blocks, 512 thr.
// wave w: m-tile (w&3) of 16 agents, dcol group n0 = 2*cg + (w>>2);
// its 4 ntiles {n0, n0+8, n0+16, n0+24} = i,f,g,o for its 16 dcols ->
// LSTM pointwise update entirely in registers.
__global__ __launch_bounds__(512) void lstm_step(
    const float* __restrict__ pos,      // compact N x 2
    const float* __restrict__ sh,       // N x 128
    const float* __restrict__ We, const float* __restrict__ be,
    const _Float16* __restrict__ WfH,   // [32 nt][10 ki][64 ln][8] f16 hi
    const _Float16* __restrict__ WfL,   // same, lo*2048
    const float* __restrict__ bsum,
    float* __restrict__ h, float* __restrict__ c,
    int firstStep)
{
    __shared__ __align__(16) _Float16 AH[4][KI][64][8];   // 40 KB
    __shared__ __align__(16) _Float16 AL[4][KI][64][8];   // 40 KB
    int cg  = blockIdx.x & 3;
    int a0  = (blockIdx.x >> 2) * 64;
    int tid = threadIdx.x;

    // ---- stage x = [emb(pos) | sh | h] for 64 agents as split-f16 fragments ----
    for (int u = tid; u < 64 * (KTOT / 8); u += 512) {  // 2560 units
        int a = u / 40, kg = u - a * 40;
        int ga = a0 + a;
        int k0 = kg * 8;
        float v[8];
        if (k0 < EDIM) {
            float px = pos[ga * 2], py = pos[ga * 2 + 1];
#pragma unroll
            for (int j = 0; j < 8; j++) {
                int k = k0 + j;
                v[j] = fmaf(px, We[k * 2], fmaf(py, We[k * 2 + 1], be[k]));
            }
        } else if (k0 < EDIM + HDIM) {
#pragma unroll
            for (int j = 0; j < 8; j++)
                v[j] = firstStep ? 0.f : sh[(unsigned)ga * HDIM + (k0 - EDIM + j)];
        } else {
#pragma unroll
            for (int j = 0; j < 8; j++)
                v[j] = h[(unsigned)ga * HDIM + (k0 - EDIM - HDIM + j)];
        }
        f16x8 hi8, lo8;
#pragma unroll
        for (int j = 0; j < 8; j++) {
            _Float16 hv = (_Float16)v[j];
            hi8[j] = hv;
            lo8[j] = (_Float16)((v[j] - (float)hv) * LOSCALE);
        }
        int m = a >> 4, ki = kg >> 2, ln = (a & 15) | ((kg & 3) << 4);
        *(f16x8*)&AH[m][ki][ln][0] = hi8;
        *(f16x8*)&AL[m][ki][ln][0] = lo8;
    }
    __syncthreads();

    int wave = tid >> 6, lane = tid & 63;
    int m  = wave & 3;
    int ng = wave >> 2;
    int n0 = 2 * cg + ng;
    int dcol = 32 * cg + 16 * ng + (lane & 15);

    f32x4 acc[4], accL[4];
#pragma unroll
    for (int g = 0; g < 4; g++) {
        float bb = bsum[dcol + g * 128];
        f32x4 z; z[0] = bb; z[1] = bb; z[2] = bb; z[3] = bb;
        acc[g] = z;
        f32x4 zz; zz[0] = 0.f; zz[1] = 0.f; zz[2] = 0.f; zz[3] = 0.f;
        accL[g] = zz;
    }

#pragma unroll
    for (int ki = 0; ki < KI; ki++) {
        f16x8 ah = *(const f16x8*)&AH[m][ki][lane][0];
        f16x8 al = *(const f16x8*)&AL[m][ki][lane][0];
#pragma unroll
        for (int g = 0; g < 4; g++) {
            int nt = n0 + 8 * g;
            size_t off = (size_t)((nt * KI + ki) * 64 + lane) * 8;
            f16x8 bh = *(const f16x8*)&WfH[off];
            f16x8 bl = *(const f16x8*)&WfL[off];
            acc[g]  = __builtin_amdgcn_mfma_f32_16x16x32_f16(ah, bh, acc[g],  0, 0, 0);
            accL[g] = __builtin_amdgcn_mfma_f32_16x16x32_f16(al, bh, accL[g], 0, 0, 0);
            accL[g] = __builtin_amdgcn_mfma_f32_16x16x32_f16(ah, bl, accL[g], 0, 0, 0);
        }
    }

    // ---- LSTM pointwise update, fully in registers ----
    const float inv = 1.0f / LOSCALE;
#pragma unroll
    for (int r = 0; r < 4; r++) {
        int alc = (lane >> 4) * 4 + r;      // row within m-tile (C/D mapping)
        int ga  = a0 + 16 * m + alc;
        float vi = fmaf(accL[0][r], inv, acc[0][r]);
        float vf = fmaf(accL[1][r], inv, acc[1][r]);
        float vg = fmaf(accL[2][r], inv, acc[2][r]);
        float vo = fmaf(accL[3][r], inv, acc[3][r]);
        float ig = 1.f / (1.f + expf(-vi));
        float fg = 1.f / (1.f + expf(-vf));
        float gg = tanhf(vg);
        float og = 1.f / (1.f + expf(-vo));
        float cold = c[(unsigned)ga * HDIM + dcol];
        float cn = fmaf(fg, cold, ig * gg);
        float hn = og * tanhf(cn);
        c[(unsigned)ga * HDIM + dcol] = cn;
        h[(unsigned)ga * HDIM + dcol] = hn;
    }
}

// ---------------- decoder tail: delta = h@Wd^T + bd; last += delta ----------------
__global__ __launch_bounds__(256) void decode_step(
    const float* __restrict__ h, const float* __restrict__ Wd,
    const float* __restrict__ bd, float* __restrict__ last,
    float* __restrict__ out, int step)
{
    int a    = blockIdx.x * 4 + (threadIdx.x >> 6);
    int lane = threadIdx.x & 63;
    const float* hr = h + (unsigned)a * HDIM;
    float h0 = hr[lane], h1 = hr[lane + 64];
    float dx = fmaf(h0, Wd[lane],       h1 * Wd[lane + 64]);
    float dy = fmaf(h0, Wd[128 + lane], h1 * Wd[192 + lane]);
#pragma unroll
    for (int off = 32; off; off >>= 1) {
        dx += __shfl_down(dx, off);
        dy += __shfl_down(dy, off);
    }
    if (lane == 0) {
        float lx = last[a * 2 + 0] + dx + bd[0];
        float ly = last[a * 2 + 1] + dy + bd[1];
        last[a * 2 + 0] = lx;
        last[a * 2 + 1] = ly;
        if (a == 0) {
            out[(8 + step) * 2 + 0] = lx;
            out[(8 + step) * 2 + 1] = ly;
        }
    }
}

extern "C" void kernel_launch(void* const* d_in, const int* in_sizes, int n_in,
                              void* d_out, int out_size, void* d_ws, size_t ws_size,
                              hipStream_t stream)
{
    const float* tracks = (const float*)d_in[0];
    const float* We     = (const float*)d_in[1];
    const float* be     = (const float*)d_in[2];
    const float* Wih    = (const float*)d_in[3];
    const float* Whh    = (const float*)d_in[4];
    const float* bih    = (const float*)d_in[5];
    const float* bhh    = (const float*)d_in[6];
    const float* Wd     = (const float*)d_in[7];
    const float* bd     = (const float*)d_in[8];
    float* out = (float*)d_out;
    float* ws  = (float*)d_ws;

    float*     h      = ws;
    float*     c      = ws + 524288;
    float*     sh     = ws + 1048576;
    float*     last   = ws + 1572864;
    float*     bsum   = ws + 1581056;
    float*     posAll = ws + 1581568;
    _Float16*  WfH    = (_Float16*)(ws + 1638912);
    _Float16*  WfL    = (_Float16*)(ws + 1720832);

    init_kernel<<<2048, 256, 0, stream>>>(tracks, Wih, Whh, bih, bhh,
                                          h, c, last, WfH, WfL, bsum, posAll, out);

    // step 0: x0 = [emb(tracks[:,0]) | zeros], h=c=0
    lstm_step<<<256, 512, 0, stream>>>(posAll, sh, We, be, WfH, WfL, bsum, h, c, 1);

    // encoder: t = 0..6
    for (int t = 0; t < T_IN - 1; t++) {
        const float* pos = posAll + (size_t)t * N_AG * 2;
        social_pool<<<N_AG, 512, 0, stream>>>(pos, h, sh);
        lstm_step<<<256, 512, 0, stream>>>(pos, sh, We, be, WfH, WfL, bsum, h, c, 0);
    }

    // decoder: 12 steps
    for (int s = 0; s < PRELEN; s++) {
        social_pool<<<N_AG, 512, 0, stream>>>(last, h, sh);
        lstm_step<<<256, 512, 0, stream>>>(last, sh, We, be, WfH, WfL, bsum, h, c, 0);
        decode_step<<<N_AG / 4, 256, 0, stream>>>(h, Wd, bd, last, out, s);
    }
}